// Round 3
// baseline (138.058 us; speedup 1.0000x reference)
//
#include <hip/hip_runtime.h>
#include <hip/hip_cooperative_groups.h>
#include <math.h>

#define EPSF 1e-7f

constexpr int B = 16, M = 128, N = 25200, C = 80;
constexpr int THREADS = 256;
constexpr int KN = 2;                       // n's per thread
constexpr int NPB = THREADS * KN;           // 512 n's per block
constexpr int NBLK_X = (N + NPB - 1) / NPB; // 50
constexpr int NBLOCKS = NBLK_X * B;         // 800

namespace cg = cooperative_groups;

__device__ __forceinline__ double wave_sum(double v) {
#pragma unroll
    for (int off = 32; off > 0; off >>= 1) v += __shfl_down(v, off, 64);
    return v;
}

__global__ __launch_bounds__(256) void detect_fused(
    const float* __restrict__ label_box, const float* __restrict__ box,
    const float* __restrict__ prb, const float* __restrict__ cls,
    const int* __restrict__ label_cls, double* __restrict__ partial,
    float* __restrict__ out)
{
    __shared__ float4 s_lb[M];    // compacted valid label boxes (original order)
    __shared__ float  s_area[M];  // their areas
    __shared__ int    s_ccls[M];  // their classes (compacted)
    __shared__ int    s_cnt[4];
    __shared__ int    s_mcount;

    const int b = blockIdx.y;
    const int t = threadIdx.x;
    const int lane = t & 63;
    const int wid  = t >> 6;

    // ---- stage + order-preserving compaction of valid (any-nonzero) boxes ----
    float4 a4 = make_float4(0.f, 0.f, 0.f, 0.f);
    bool valid = false;
    if (t < M) {
        a4 = reinterpret_cast<const float4*>(label_box)[b * M + t];
        valid = (a4.x != 0.f) | (a4.y != 0.f) | (a4.z != 0.f) | (a4.w != 0.f);
    }
    unsigned long long ball = __ballot(valid);
    if (lane == 0) s_cnt[wid] = __popcll(ball);
    __syncthreads();
    if (valid) {
        int base = 0;
#pragma unroll
        for (int w = 0; w < 4; ++w) if (w < wid) base += s_cnt[w];
        int c = base + __popcll(ball & ((1ull << lane) - 1ull));
        s_lb[c]   = a4;
        s_area[c] = fmaxf(a4.z - a4.x, 0.0f) * fmaxf(a4.w - a4.y, 0.0f);
        s_ccls[c] = label_cls[b * M + t];
    }
    if (t == 0) s_mcount = s_cnt[0] + s_cnt[1] + s_cnt[2] + s_cnt[3];
    __syncthreads();
    const int mc = s_mcount;

    // ---- per-thread n state ----
    const int nbase = blockIdx.x * NPB + t;
    float4 bx[KN];
    float  areab[KN];   // exact w2*h2 (reference area_b)
    float  areabe[KN];  // areab + EPSF (monotone-equivalent for argmax compare)
    bool   act[KN];
    float  ibest[KN], ubest[KN];
    int    bc[KN];
#pragma unroll
    for (int k = 0; k < KN; ++k) {
        const int n = nbase + k * THREADS;
        act[k] = (n < N);
        bx[k] = act[k] ? reinterpret_cast<const float4*>(box)[b * N + n]
                       : make_float4(0.f, 0.f, 0.f, 0.f);
        float w2 = fmaxf(bx[k].z - bx[k].x, 0.0f);
        float h2 = fmaxf(bx[k].w - bx[k].y, 0.0f);
        areab[k]  = w2 * h2;
        areabe[k] = areab[k] + EPSF;
        ibest[k] = 0.0f;  // inter of best
        ubest[k] = 1.0f;  // uni of best (any positive; best iou = 0/1 = 0)
        bc[k]    = 0;
    }

    // ---- division-free argmax over compacted valid boxes ----
#pragma unroll 2
    for (int m = 0; m < mc; ++m) {
        const float4 a  = s_lb[m];
        const float  aa = s_area[m];
#pragma unroll
        for (int k = 0; k < KN; ++k) {
            float ix1 = fmaxf(a.x, bx[k].x);
            float iy1 = fmaxf(a.y, bx[k].y);
            float ix2 = fminf(a.z, bx[k].z);
            float iy2 = fminf(a.w, bx[k].w);
            float inter = fmaxf(ix2 - ix1, 0.0f) * fmaxf(iy2 - iy1, 0.0f);
            float uni = (aa + areabe[k]) - inter;  // ~uni+eps, monotone in iou
            // inter/uni > ibest/ubest  <=>  inter*ubest > ibest*uni  (all >= 0)
            if (inter * ubest[k] > ibest[k] * uni) {
                ibest[k] = inter; ubest[k] = uni; bc[k] = m;
            }
        }
    }

    // ---- epilogue: exact thresholds + losses ----
    double v_pos = 0.0, v_neg = 0.0, v_ciou = 0.0;
    double v_logp = 0.0, v_log1mp = 0.0, v_nll = 0.0;

#pragma unroll
    for (int k = 0; k < KN; ++k) {
        if (!act[k] || mc == 0) continue;
        const int n = nbase + k * THREADS;

        // recompute winner's IoU in exact reference rounding order
        const float4 a = s_lb[bc[k]];
        float ix1 = fmaxf(a.x, bx[k].x);
        float iy1 = fmaxf(a.y, bx[k].y);
        float ix2 = fminf(a.z, bx[k].z);
        float iy2 = fminf(a.w, bx[k].w);
        float inter = fmaxf(ix2 - ix1, 0.0f) * fmaxf(iy2 - iy1, 0.0f);
        float best = inter / (((s_area[bc[k]] + areab[k]) - inter) + EPSF);

        const bool pos = best > 0.7f;
        const bool neg = (best > 0.0f) && (best < 0.3f);
        if (!(pos | neg)) continue;

        const float p = fminf(fmaxf(prb[b * N + n], EPSF), 1.0f - EPSF);

        if (pos) {
            v_pos += 1.0;
            v_logp += (double)(-logf(p));

            float w1 = fmaxf(a.z - a.x, 0.0f);
            float h1 = fmaxf(a.w - a.y, 0.0f);
            float w2 = fmaxf(bx[k].z - bx[k].x, 0.0f);
            float h2 = fmaxf(bx[k].w - bx[k].y, 0.0f);
            float uni = w1 * h1 + w2 * h2 - inter;
            float iou = inter / (uni + EPSF);
            float cw = fmaxf(a.z, bx[k].z) - fminf(a.x, bx[k].x);
            float ch = fmaxf(a.w, bx[k].w) - fminf(a.y, bx[k].y);
            float c2 = cw * cw + ch * ch + EPSF;
            float dx = (a.x + a.z - bx[k].x - bx[k].z) * 0.5f;
            float dy = (a.y + a.w - bx[k].y - bx[k].w) * 0.5f;
            float rho2 = dx * dx + dy * dy;
            float dat = atanf(w1 / (h1 + EPSF)) - atanf(w2 / (h2 + EPSF));
            float v = 0.40528473456935109f * dat * dat; // 4/pi^2
            float alpha = v / (1.0f - iou + v + EPSF);
            float ciou = iou - rho2 / c2 - alpha * v;
            v_ciou += (double)(1.0f - ciou);

            float pc = cls[(size_t)(b * N + n) * C + s_ccls[bc[k]]];
            pc = fminf(fmaxf(pc, EPSF), 1.0f);
            v_nll += (double)(-logf(pc));
        } else { // neg
            v_neg += 1.0;
            v_log1mp += (double)(-logf(1.0f - p));
        }
    }

    // ---- deterministic block reduction (double) ----
    __shared__ double s_red[6][4];
    double vals[6] = { v_pos, v_neg, v_ciou, v_logp, v_log1mp, v_nll };
#pragma unroll
    for (int kk = 0; kk < 6; ++kk) {
        double v = wave_sum(vals[kk]);
        if (lane == 0) s_red[kk][wid] = v;
    }
    __syncthreads();

    const int bid = blockIdx.y * gridDim.x + blockIdx.x;
    if (t == 0) {
#pragma unroll
        for (int kk = 0; kk < 6; ++kk)
            partial[(size_t)bid * 6 + kk] =
                s_red[kk][0] + s_red[kk][1] + s_red[kk][2] + s_red[kk][3];
        __threadfence();
    }

    // ---- grid-wide barrier, then block 0 finalizes ----
    cg::this_grid().sync();

    if (bid == 0) {
        double acc[6] = {0.0, 0.0, 0.0, 0.0, 0.0, 0.0};
        for (int i = t; i < NBLOCKS; i += THREADS) {
#pragma unroll
            for (int kk = 0; kk < 6; ++kk) acc[kk] += partial[(size_t)i * 6 + kk];
        }
        __shared__ double s_fin[6][4];
#pragma unroll
        for (int kk = 0; kk < 6; ++kk) {
            double v = wave_sum(acc[kk]);
            if (lane == 0) s_fin[kk][wid] = v;
        }
        __syncthreads();
        if (t == 0) {
            double tot[6];
#pragma unroll
            for (int kk = 0; kk < 6; ++kk)
                tot[kk] = s_fin[kk][0] + s_fin[kk][1] + s_fin[kk][2] + s_fin[kk][3];
            const double npos = fmax(tot[0], 1.0);
            const double nneg = fmax(tot[1], 1.0);
            out[0] = (float)(tot[2] / npos);                 // box_loss
            out[1] = (float)(tot[3] / npos + tot[4] / nneg); // prb_loss
            out[2] = (float)(tot[5] / npos);                 // cls_loss
        }
    }
}

extern "C" void kernel_launch(void* const* d_in, const int* in_sizes, int n_in,
                              void* d_out, int out_size, void* d_ws, size_t ws_size,
                              hipStream_t stream) {
    const float* label_box = (const float*)d_in[0];
    const float* box       = (const float*)d_in[1];
    const float* prb       = (const float*)d_in[2];
    const float* cls       = (const float*)d_in[3];
    const int*   label_cls = (const int*)d_in[4];
    float*  out     = (float*)d_out;
    double* partial = (double*)d_ws; // NBLOCKS*6 doubles = 38.4 KB

    void* args[] = { (void*)&label_box, (void*)&box, (void*)&prb, (void*)&cls,
                     (void*)&label_cls, (void*)&partial, (void*)&out };
    dim3 grid(NBLK_X, B);
    dim3 block(THREADS);
    hipLaunchCooperativeKernel((const void*)detect_fused, grid, block, args, 0, stream);
}

// Round 4
// 45.806 us; speedup vs baseline: 3.0140x; 3.0140x over previous
//
#include <hip/hip_runtime.h>
#include <math.h>

#define EPSF 1e-7f

constexpr int B = 16, M = 128, N = 25200, C = 80;
constexpr int THREADS = 256;
constexpr int KN = 2;                       // n's per thread
constexpr int NPB = THREADS * KN;           // 512 n's per block
constexpr int NBLK_X = (N + NPB - 1) / NPB; // 50
constexpr int NBLOCKS = NBLK_X * B;         // 800

__device__ __forceinline__ double wave_sum(double v) {
#pragma unroll
    for (int off = 32; off > 0; off >>= 1) v += __shfl_down(v, off, 64);
    return v;
}

__global__ __launch_bounds__(256) void detect_onepass(
    const float* __restrict__ label_box, const float* __restrict__ box,
    const float* __restrict__ prb, const float* __restrict__ cls,
    const int* __restrict__ label_cls, unsigned* __restrict__ counter,
    double* __restrict__ partial, float* __restrict__ out)
{
    __shared__ float4 s_lb[M];    // compacted valid label boxes (original order)
    __shared__ float  s_area[M];  // their areas
    __shared__ int    s_ccls[M];  // their classes (compacted)
    __shared__ int    s_cnt[4];
    __shared__ int    s_mcount;
    __shared__ int    s_last;

    const int b = blockIdx.y;
    const int t = threadIdx.x;
    const int lane = t & 63;
    const int wid  = t >> 6;

    // ---- stage + order-preserving compaction of valid (any-nonzero) boxes ----
    float4 a4 = make_float4(0.f, 0.f, 0.f, 0.f);
    bool valid = false;
    if (t < M) {
        a4 = reinterpret_cast<const float4*>(label_box)[b * M + t];
        valid = (a4.x != 0.f) | (a4.y != 0.f) | (a4.z != 0.f) | (a4.w != 0.f);
    }
    unsigned long long ball = __ballot(valid);
    if (lane == 0) s_cnt[wid] = __popcll(ball);
    __syncthreads();
    if (valid) {
        int base = 0;
#pragma unroll
        for (int w = 0; w < 4; ++w) if (w < wid) base += s_cnt[w];
        int c = base + __popcll(ball & ((1ull << lane) - 1ull));
        s_lb[c]   = a4;
        s_area[c] = fmaxf(a4.z - a4.x, 0.0f) * fmaxf(a4.w - a4.y, 0.0f);
        s_ccls[c] = label_cls[b * M + t];
    }
    if (t == 0) s_mcount = s_cnt[0] + s_cnt[1] + s_cnt[2] + s_cnt[3];
    __syncthreads();
    const int mc = s_mcount;

    // ---- per-thread n state ----
    const int nbase = blockIdx.x * NPB + t;
    float4 bx[KN];
    float  areab[KN];   // exact w2*h2 (reference area_b)
    float  areabe[KN];  // areab + EPSF
    bool   act[KN];
    float  ibest[KN], Sbest[KN];
    int    bc[KN];
#pragma unroll
    for (int k = 0; k < KN; ++k) {
        const int n = nbase + k * THREADS;
        act[k] = (n < N);
        bx[k] = act[k] ? reinterpret_cast<const float4*>(box)[b * N + n]
                       : make_float4(0.f, 0.f, 0.f, 0.f);
        float w2 = fmaxf(bx[k].z - bx[k].x, 0.0f);
        float h2 = fmaxf(bx[k].w - bx[k].y, 0.0f);
        areab[k]  = w2 * h2;
        areabe[k] = areab[k] + EPSF;
        ibest[k] = 0.0f;  // inter of best
        Sbest[k] = 1.0f;  // S (= area_a+area_b+eps) of best; any positive works
        bc[k]    = 0;
    }

    // ---- division-free argmax: iou1>iou2 <=> inter1*S2 > inter2*S1 ----
#pragma unroll 2
    for (int m = 0; m < mc; ++m) {
        const float4 a  = s_lb[m];
        const float  aa = s_area[m];
#pragma unroll
        for (int k = 0; k < KN; ++k) {
            float ix1 = fmaxf(a.x, bx[k].x);
            float iy1 = fmaxf(a.y, bx[k].y);
            float ix2 = fminf(a.z, bx[k].z);
            float iy2 = fminf(a.w, bx[k].w);
            float inter = fmaxf(ix2 - ix1, 0.0f) * fmaxf(iy2 - iy1, 0.0f);
            float S = aa + areabe[k];   // uni = S - inter; cross terms cancel
            if (inter * Sbest[k] > ibest[k] * S) {
                ibest[k] = inter; Sbest[k] = S; bc[k] = m;
            }
        }
    }

    // ---- epilogue: exact thresholds + losses ----
    double v_pos = 0.0, v_neg = 0.0, v_ciou = 0.0;
    double v_logp = 0.0, v_log1mp = 0.0, v_nll = 0.0;

#pragma unroll
    for (int k = 0; k < KN; ++k) {
        if (!act[k] || mc == 0) continue;
        const int n = nbase + k * THREADS;

        // recompute winner's IoU in exact reference rounding order
        const float4 a = s_lb[bc[k]];
        float ix1 = fmaxf(a.x, bx[k].x);
        float iy1 = fmaxf(a.y, bx[k].y);
        float ix2 = fminf(a.z, bx[k].z);
        float iy2 = fminf(a.w, bx[k].w);
        float inter = fmaxf(ix2 - ix1, 0.0f) * fmaxf(iy2 - iy1, 0.0f);
        float best = inter / (((s_area[bc[k]] + areab[k]) - inter) + EPSF);

        const bool pos = best > 0.7f;
        const bool neg = (best > 0.0f) && (best < 0.3f);
        if (!(pos | neg)) continue;

        const float p = fminf(fmaxf(prb[b * N + n], EPSF), 1.0f - EPSF);

        if (pos) {
            v_pos += 1.0;
            v_logp += (double)(-logf(p));

            float w1 = fmaxf(a.z - a.x, 0.0f);
            float h1 = fmaxf(a.w - a.y, 0.0f);
            float w2 = fmaxf(bx[k].z - bx[k].x, 0.0f);
            float h2 = fmaxf(bx[k].w - bx[k].y, 0.0f);
            float uni = w1 * h1 + w2 * h2 - inter;
            float iou = inter / (uni + EPSF);
            float cw = fmaxf(a.z, bx[k].z) - fminf(a.x, bx[k].x);
            float ch = fmaxf(a.w, bx[k].w) - fminf(a.y, bx[k].y);
            float c2 = cw * cw + ch * ch + EPSF;
            float dx = (a.x + a.z - bx[k].x - bx[k].z) * 0.5f;
            float dy = (a.y + a.w - bx[k].y - bx[k].w) * 0.5f;
            float rho2 = dx * dx + dy * dy;
            float dat = atanf(w1 / (h1 + EPSF)) - atanf(w2 / (h2 + EPSF));
            float v = 0.40528473456935109f * dat * dat; // 4/pi^2
            float alpha = v / (1.0f - iou + v + EPSF);
            float ciou = iou - rho2 / c2 - alpha * v;
            v_ciou += (double)(1.0f - ciou);

            float pc = cls[(size_t)(b * N + n) * C + s_ccls[bc[k]]];
            pc = fminf(fmaxf(pc, EPSF), 1.0f);
            v_nll += (double)(-logf(pc));
        } else { // neg
            v_neg += 1.0;
            v_log1mp += (double)(-logf(1.0f - p));
        }
    }

    // ---- deterministic block reduction (double) ----
    __shared__ double s_red[6][4];
    double vals[6] = { v_pos, v_neg, v_ciou, v_logp, v_log1mp, v_nll };
#pragma unroll
    for (int kk = 0; kk < 6; ++kk) {
        double v = wave_sum(vals[kk]);
        if (lane == 0) s_red[kk][wid] = v;
    }
    __syncthreads();

    const int bid = blockIdx.y * gridDim.x + blockIdx.x;
    if (t == 0) {
#pragma unroll
        for (int kk = 0; kk < 6; ++kk)
            partial[(size_t)bid * 6 + kk] =
                s_red[kk][0] + s_red[kk][1] + s_red[kk][2] + s_red[kk][3];
        __threadfence();                       // device-scope release of partials
        unsigned old = atomicAdd(counter, 1u); // device-scope by default
        s_last = (old == NBLOCKS - 1) ? 1 : 0;
    }
    __syncthreads();

    // ---- last block to finish reduces the fixed-order partial array ----
    if (s_last) {
        __threadfence();  // acquire: invalidate caches so partials are fresh
        double acc[6] = {0.0, 0.0, 0.0, 0.0, 0.0, 0.0};
        for (int i = t; i < NBLOCKS; i += THREADS) {
#pragma unroll
            for (int kk = 0; kk < 6; ++kk) acc[kk] += partial[(size_t)i * 6 + kk];
        }
        __shared__ double s_fin[6][4];
#pragma unroll
        for (int kk = 0; kk < 6; ++kk) {
            double v = wave_sum(acc[kk]);
            if (lane == 0) s_fin[kk][wid] = v;
        }
        __syncthreads();
        if (t == 0) {
            double tot[6];
#pragma unroll
            for (int kk = 0; kk < 6; ++kk)
                tot[kk] = s_fin[kk][0] + s_fin[kk][1] + s_fin[kk][2] + s_fin[kk][3];
            const double npos = fmax(tot[0], 1.0);
            const double nneg = fmax(tot[1], 1.0);
            out[0] = (float)(tot[2] / npos);                 // box_loss
            out[1] = (float)(tot[3] / npos + tot[4] / nneg); // prb_loss
            out[2] = (float)(tot[5] / npos);                 // cls_loss
        }
    }
}

extern "C" void kernel_launch(void* const* d_in, const int* in_sizes, int n_in,
                              void* d_out, int out_size, void* d_ws, size_t ws_size,
                              hipStream_t stream) {
    const float* label_box = (const float*)d_in[0];
    const float* box       = (const float*)d_in[1];
    const float* prb       = (const float*)d_in[2];
    const float* cls       = (const float*)d_in[3];
    const int*   label_cls = (const int*)d_in[4];
    float* out = (float*)d_out;

    unsigned* counter = (unsigned*)d_ws;                       // 4 bytes @ offset 0
    double*   partial = (double*)((char*)d_ws + 64);           // NBLOCKS*6 doubles

    // zero the ticket counter each call (graph-capturable async memset)
    hipMemsetAsync(counter, 0, sizeof(unsigned), stream);

    dim3 grid(NBLK_X, B);
    detect_onepass<<<grid, THREADS, 0, stream>>>(
        label_box, box, prb, cls, label_cls, counter, partial, out);
}

// Round 5
// 33.172 us; speedup vs baseline: 4.1619x; 1.3809x over previous
//
#include <hip/hip_runtime.h>
#include <math.h>

#define EPSF 1e-7f

constexpr int B = 16, M = 128, N = 25200, C = 80;
constexpr int THREADS = 256;
constexpr int NBLK_X = 48;                  // 48*16 = 768 blocks = exactly 3/CU
constexpr int NPB = N / NBLK_X;             // 525 n's per block (exact: 48*525=25200)
constexpr int NBLOCKS = NBLK_X * B;         // 768

__device__ __forceinline__ double wave_sum(double v) {
#pragma unroll
    for (int off = 32; off > 0; off >>= 1) v += __shfl_down(v, off, 64);
    return v;
}

// single-slot division-free argmax over compacted boxes (used for the 13-lane tail)
__device__ __forceinline__ void argmax_one(
    const float4* s_lb, const float* s_area, int mc, const float4& bx,
    float areabe, float& ibest, float& Sbest, int& bc)
{
    for (int m = 0; m < mc; ++m) {
        const float4 a = s_lb[m];
        float ix1 = fmaxf(a.x, bx.x);
        float iy1 = fmaxf(a.y, bx.y);
        float ix2 = fminf(a.z, bx.z);
        float iy2 = fminf(a.w, bx.w);
        float inter = fmaxf(ix2 - ix1, 0.0f) * fmaxf(iy2 - iy1, 0.0f);
        float S = s_area[m] + areabe;
        if (inter * Sbest > ibest * S) { ibest = inter; Sbest = S; bc = m; }
    }
}

__global__ __launch_bounds__(256) void detect_main(
    const float* __restrict__ label_box, const float* __restrict__ box,
    const float* __restrict__ prb, const float* __restrict__ cls,
    const int* __restrict__ label_cls, double* __restrict__ partial)
{
    __shared__ float4 s_lb[M];    // compacted valid label boxes (original order)
    __shared__ float  s_area[M];  // their areas
    __shared__ int    s_ccls[M];  // their classes (compacted)
    __shared__ int    s_cnt[4];
    __shared__ int    s_mcount;

    const int b = blockIdx.y;
    const int t = threadIdx.x;
    const int lane = t & 63;
    const int wid  = t >> 6;

    // ---- stage + order-preserving compaction of valid (any-nonzero) boxes ----
    float4 a4 = make_float4(0.f, 0.f, 0.f, 0.f);
    bool valid = false;
    if (t < M) {
        a4 = reinterpret_cast<const float4*>(label_box)[b * M + t];
        valid = (a4.x != 0.f) | (a4.y != 0.f) | (a4.z != 0.f) | (a4.w != 0.f);
    }
    unsigned long long ball = __ballot(valid);
    if (lane == 0) s_cnt[wid] = __popcll(ball);
    __syncthreads();
    if (valid) {
        int base = 0;
#pragma unroll
        for (int w = 0; w < 4; ++w) if (w < wid) base += s_cnt[w];
        int c = base + __popcll(ball & ((1ull << lane) - 1ull));
        s_lb[c]   = a4;
        s_area[c] = fmaxf(a4.z - a4.x, 0.0f) * fmaxf(a4.w - a4.y, 0.0f);
        s_ccls[c] = label_cls[b * M + t];
    }
    if (t == 0) s_mcount = s_cnt[0] + s_cnt[1] + s_cnt[2] + s_cnt[3];
    __syncthreads();
    const int mc = s_mcount;

    // ---- per-thread n state: 2 full slots + 13-lane tail on wave (blockIdx.x&3) ----
    const int nbase = blockIdx.x * NPB;     // block covers [nbase, nbase+525)
    const int n0 = nbase + t;
    const int n1 = nbase + 256 + t;         // 256+255 = 511 < 525, always active

    float4 bx0 = reinterpret_cast<const float4*>(box)[b * N + n0];
    float4 bx1 = reinterpret_cast<const float4*>(box)[b * N + n1];
    float areab0 = fmaxf(bx0.z - bx0.x, 0.0f) * fmaxf(bx0.w - bx0.y, 0.0f);
    float areab1 = fmaxf(bx1.z - bx1.x, 0.0f) * fmaxf(bx1.w - bx1.y, 0.0f);
    float areabe0 = areab0 + EPSF;
    float areabe1 = areab1 + EPSF;
    float ibest0 = 0.0f, Sbest0 = 1.0f; int bc0 = 0;
    float ibest1 = 0.0f, Sbest1 = 1.0f; int bc1 = 0;

    // ---- fused 2-slot division-free argmax ----
#pragma unroll 2
    for (int m = 0; m < mc; ++m) {
        const float4 a  = s_lb[m];
        const float  aa = s_area[m];
        {
            float ix1 = fmaxf(a.x, bx0.x);
            float iy1 = fmaxf(a.y, bx0.y);
            float ix2 = fminf(a.z, bx0.z);
            float iy2 = fminf(a.w, bx0.w);
            float inter = fmaxf(ix2 - ix1, 0.0f) * fmaxf(iy2 - iy1, 0.0f);
            float S = aa + areabe0;
            if (inter * Sbest0 > ibest0 * S) { ibest0 = inter; Sbest0 = S; bc0 = m; }
        }
        {
            float ix1 = fmaxf(a.x, bx1.x);
            float iy1 = fmaxf(a.y, bx1.y);
            float ix2 = fminf(a.z, bx1.z);
            float iy2 = fminf(a.w, bx1.w);
            float inter = fmaxf(ix2 - ix1, 0.0f) * fmaxf(iy2 - iy1, 0.0f);
            float S = aa + areabe1;
            if (inter * Sbest1 > ibest1 * S) { ibest1 = inter; Sbest1 = S; bc1 = m; }
        }
    }

    // ---- tail: n = nbase + 512 + lane for 13 lanes of wave (blockIdx.x&3) ----
    const int tw = blockIdx.x & 3;
    const bool tact = (wid == tw) && (lane < (NPB - 512));   // 13 lanes
    const int n2 = nbase + 512 + lane;
    float4 bx2 = make_float4(0.f, 0.f, 0.f, 0.f);
    float areab2 = 0.0f, areabe2 = EPSF;
    float ibest2 = 0.0f, Sbest2 = 1.0f; int bc2 = 0;
    if (tact) {
        bx2 = reinterpret_cast<const float4*>(box)[b * N + n2];
        areab2 = fmaxf(bx2.z - bx2.x, 0.0f) * fmaxf(bx2.w - bx2.y, 0.0f);
        areabe2 = areab2 + EPSF;
        argmax_one(s_lb, s_area, mc, bx2, areabe2, ibest2, Sbest2, bc2);
    }

    // ---- epilogue: exact thresholds + losses ----
    double v_pos = 0.0, v_neg = 0.0, v_ciou = 0.0;
    double v_logp = 0.0, v_log1mp = 0.0, v_nll = 0.0;

    auto epilogue = [&](int n, const float4& bx, float areab, int bc) {
        // recompute winner's IoU in exact reference rounding order
        const float4 a = s_lb[bc];
        float ix1 = fmaxf(a.x, bx.x);
        float iy1 = fmaxf(a.y, bx.y);
        float ix2 = fminf(a.z, bx.z);
        float iy2 = fminf(a.w, bx.w);
        float inter = fmaxf(ix2 - ix1, 0.0f) * fmaxf(iy2 - iy1, 0.0f);
        float best = inter / (((s_area[bc] + areab) - inter) + EPSF);

        const bool pos = best > 0.7f;
        const bool neg = (best > 0.0f) && (best < 0.3f);
        if (!(pos | neg)) return;

        const float p = fminf(fmaxf(prb[b * N + n], EPSF), 1.0f - EPSF);

        if (pos) {
            v_pos += 1.0;
            v_logp += (double)(-logf(p));

            float w1 = fmaxf(a.z - a.x, 0.0f);
            float h1 = fmaxf(a.w - a.y, 0.0f);
            float w2 = fmaxf(bx.z - bx.x, 0.0f);
            float h2 = fmaxf(bx.w - bx.y, 0.0f);
            float uni = w1 * h1 + w2 * h2 - inter;
            float iou = inter / (uni + EPSF);
            float cw = fmaxf(a.z, bx.z) - fminf(a.x, bx.x);
            float ch = fmaxf(a.w, bx.w) - fminf(a.y, bx.y);
            float c2 = cw * cw + ch * ch + EPSF;
            float dx = (a.x + a.z - bx.x - bx.z) * 0.5f;
            float dy = (a.y + a.w - bx.y - bx.w) * 0.5f;
            float rho2 = dx * dx + dy * dy;
            float dat = atanf(w1 / (h1 + EPSF)) - atanf(w2 / (h2 + EPSF));
            float v = 0.40528473456935109f * dat * dat; // 4/pi^2
            float alpha = v / (1.0f - iou + v + EPSF);
            float ciou = iou - rho2 / c2 - alpha * v;
            v_ciou += (double)(1.0f - ciou);

            float pc = cls[(size_t)(b * N + n) * C + s_ccls[bc]];
            pc = fminf(fmaxf(pc, EPSF), 1.0f);
            v_nll += (double)(-logf(pc));
        } else { // neg
            v_neg += 1.0;
            v_log1mp += (double)(-logf(1.0f - p));
        }
    };

    if (mc > 0) {
        epilogue(n0, bx0, areab0, bc0);
        epilogue(n1, bx1, areab1, bc1);
        if (tact) epilogue(n2, bx2, areab2, bc2);
    }

    // ---- deterministic block reduction (double) ----
    __shared__ double s_red[6][4];
    double vals[6] = { v_pos, v_neg, v_ciou, v_logp, v_log1mp, v_nll };
#pragma unroll
    for (int kk = 0; kk < 6; ++kk) {
        double v = wave_sum(vals[kk]);
        if (lane == 0) s_red[kk][wid] = v;
    }
    __syncthreads();

    if (t == 0) {
        const int bid = blockIdx.y * gridDim.x + blockIdx.x;
#pragma unroll
        for (int kk = 0; kk < 6; ++kk)
            partial[(size_t)bid * 6 + kk] =
                s_red[kk][0] + s_red[kk][1] + s_red[kk][2] + s_red[kk][3];
    }
}

__global__ __launch_bounds__(256) void detect_finalize(
    const double* __restrict__ partial, float* __restrict__ out)
{
    double acc[6] = {0.0, 0.0, 0.0, 0.0, 0.0, 0.0};
    for (int i = threadIdx.x; i < NBLOCKS; i += 256) {
#pragma unroll
        for (int k = 0; k < 6; ++k) acc[k] += partial[(size_t)i * 6 + k];
    }

    __shared__ double s_red[6][4];
    const int lane = threadIdx.x & 63;
    const int wid  = threadIdx.x >> 6;
#pragma unroll
    for (int k = 0; k < 6; ++k) {
        double v = wave_sum(acc[k]);
        if (lane == 0) s_red[k][wid] = v;
    }
    __syncthreads();

    if (threadIdx.x == 0) {
        double tot[6];
#pragma unroll
        for (int k = 0; k < 6; ++k)
            tot[k] = s_red[k][0] + s_red[k][1] + s_red[k][2] + s_red[k][3];

        const double npos = fmax(tot[0], 1.0);
        const double nneg = fmax(tot[1], 1.0);
        out[0] = (float)(tot[2] / npos);                 // box_loss
        out[1] = (float)(tot[3] / npos + tot[4] / nneg); // prb_loss
        out[2] = (float)(tot[5] / npos);                 // cls_loss
    }
}

extern "C" void kernel_launch(void* const* d_in, const int* in_sizes, int n_in,
                              void* d_out, int out_size, void* d_ws, size_t ws_size,
                              hipStream_t stream) {
    const float* label_box = (const float*)d_in[0];
    const float* box       = (const float*)d_in[1];
    const float* prb       = (const float*)d_in[2];
    const float* cls       = (const float*)d_in[3];
    const int*   label_cls = (const int*)d_in[4];
    float*  out     = (float*)d_out;
    double* partial = (double*)d_ws; // NBLOCKS*6 doubles = 36.9 KB

    dim3 grid(NBLK_X, B);
    detect_main<<<grid, THREADS, 0, stream>>>(label_box, box, prb, cls, label_cls, partial);
    detect_finalize<<<1, 256, 0, stream>>>(partial, out);
}